// Round 4
// baseline (226.954 us; speedup 1.0000x reference)
//
#include <hip/hip_runtime.h>

#define IN_C 64
#define OUT_C 16
#define EA_D 8
#define SCAN_BS 1024

// ---------------- h = x @ lin_w + lin_b ----------------
__global__ __launch_bounds__(256) void h_kernel(
    const float* __restrict__ x,
    const float* __restrict__ lin_w,   // [64,16]
    const float* __restrict__ lin_b,   // [16]
    float* __restrict__ h,             // [N,16]
    int n)
{
    __shared__ float s_w[IN_C * OUT_C];
    __shared__ float s_b[OUT_C];
    __shared__ float s_x[16][IN_C + 4];

    const int t = threadIdx.x;
    for (int i = t; i < IN_C * OUT_C; i += 256) s_w[i] = lin_w[i];
    if (t < OUT_C) s_b[t] = lin_b[t];

    const int nodeBase = blockIdx.x * 16;
    {
        const int lr = t >> 4;
        const int k4 = (t & 15) * 4;
        const int node = nodeBase + lr;
        float4 v = make_float4(0.f, 0.f, 0.f, 0.f);
        if (node < n) v = *(const float4*)(x + (size_t)node * IN_C + k4);
        *(float4*)(&s_x[lr][k4]) = v;
    }
    __syncthreads();

    const int lr = t >> 4;
    const int c  = t & 15;
    const int node = nodeBase + lr;
    if (node < n) {
        float acc = s_b[c];
        #pragma unroll
        for (int k = 0; k < IN_C; ++k)
            acc = fmaf(s_x[lr][k], s_w[k * OUT_C + c], acc);
        h[node * OUT_C + c] = acc;
    }
}

// ---------------- degree histogram ----------------
__global__ __launch_bounds__(256) void hist_kernel(
    const int* __restrict__ edge_index, int* __restrict__ deg, int E)
{
    const int e = blockIdx.x * 256 + threadIdx.x;
    if (e < E) atomicAdd(deg + (edge_index[e] - 1), 1);
}

// ---------------- scan phase A: per-block sums ----------------
__global__ __launch_bounds__(SCAN_BS) void scan_a(
    const int* __restrict__ deg, int* __restrict__ bsum, int n)
{
    __shared__ int s_w[16];
    const int t = threadIdx.x;
    const int i = blockIdx.x * SCAN_BS + t;
    int v = (i < n) ? deg[i] : 0;
    #pragma unroll
    for (int off = 1; off < 64; off <<= 1) v += __shfl_xor(v, off);
    const int lane = t & 63, wid = t >> 6;
    if (lane == 0) s_w[wid] = v;
    __syncthreads();
    if (wid == 0) {
        int x = (lane < 16) ? s_w[lane] : 0;
        #pragma unroll
        for (int off = 1; off < 16; off <<= 1) x += __shfl_xor(x, off);
        if (lane == 0) bsum[blockIdx.x] = x;
    }
}

// ---------------- scan phase B: single-block exclusive scan of block sums ----
__global__ __launch_bounds__(SCAN_BS) void scan_b(
    int* __restrict__ bsum, int nb, int* __restrict__ row_start, int n)
{
    __shared__ int s[SCAN_BS];
    const int t = threadIdx.x;
    const int v = (t < nb) ? bsum[t] : 0;
    s[t] = v;
    __syncthreads();
    for (int off = 1; off < SCAN_BS; off <<= 1) {
        int x = (t >= off) ? s[t - off] : 0;
        __syncthreads();
        s[t] += x;
        __syncthreads();
    }
    if (t < nb) bsum[t] = s[t] - v;          // exclusive
    if (t == 0) row_start[n] = s[nb - 1];    // total == E
}

// ---------------- scan phase C: per-block exclusive scan + offset ----------
__global__ __launch_bounds__(SCAN_BS) void scan_c(
    const int* __restrict__ deg, const int* __restrict__ bsum,
    int* __restrict__ row_start, int* __restrict__ cursor, int n)
{
    __shared__ int s_w[16];
    const int t = threadIdx.x;
    const int i = blockIdx.x * SCAN_BS + t;
    const int v = (i < n) ? deg[i] : 0;
    const int lane = t & 63, wid = t >> 6;

    int incl = v;
    #pragma unroll
    for (int off = 1; off < 64; off <<= 1) {
        int x = __shfl_up(incl, off);
        if (lane >= off) incl += x;
    }
    if (lane == 63) s_w[wid] = incl;
    __syncthreads();
    if (wid == 0) {
        int x = (lane < 16) ? s_w[lane] : 0;
        int xin = x;
        #pragma unroll
        for (int off = 1; off < 16; off <<= 1) {
            int y = __shfl_up(xin, off);
            if (lane >= off) xin += y;
        }
        if (lane < 16) s_w[lane] = xin - x;   // exclusive wave offsets
    }
    __syncthreads();

    const int excl = incl - v + s_w[wid] + bsum[blockIdx.x];
    if (i < n) { row_start[i] = excl; cursor[i] = excl; }
    if (i == n) row_start[n] = excl;          // == E (also written by scan_b)
}

// ---------------- scatter: sort edges by target row ----------------
__global__ __launch_bounds__(256) void scatter_kernel(
    const int* __restrict__ edge_index, int* __restrict__ cursor,
    uint2* __restrict__ sec, int E)
{
    const int e = blockIdx.x * 256 + threadIdx.x;
    if (e < E) {
        const int r   = edge_index[e] - 1;
        const int col = edge_index[E + e];
        const int pos = atomicAdd(cursor + r, 1);
        sec[pos] = make_uint2((unsigned)e, (unsigned)col);
    }
}

// ---------------- node kernel: one wave per node, atomic-free ----------------
// 4 quads x 16 channels: 4 edges processed in parallel; softmax within quad.
__global__ __launch_bounds__(256) void node_kernel(
    const uint2* __restrict__ sec,
    const int*   __restrict__ row_start,
    const float* __restrict__ edge_attr,   // [E,8]
    const float* __restrict__ h,           // [N,16]
    const float* __restrict__ ea_w,        // [8,16]
    const float* __restrict__ ea_b,        // [16]
    const float* __restrict__ w1,          // [16]
    const float* __restrict__ b1,          // [16]
    const float* __restrict__ w2,          // [16]
    const float* __restrict__ b2,          // [1]
    float*       __restrict__ out,         // [N,16]
    int n)
{
    __shared__ float s_eaw[EA_D * OUT_C];
    __shared__ float s_eab[OUT_C];
    __shared__ float s_w1[OUT_C], s_b1[OUT_C], s_w2[OUT_C];
    __shared__ float s_b2;

    const int t = threadIdx.x;
    if (t < 128)       s_eaw[t]       = ea_w[t];
    else if (t < 144)  s_eab[t - 128] = ea_b[t - 128];
    else if (t < 160)  s_w1[t - 144]  = w1[t - 144];
    else if (t < 176)  s_b1[t - 160]  = b1[t - 160];
    else if (t < 192)  s_w2[t - 176]  = w2[t - 176];
    else if (t == 192) s_b2           = b2[0];
    __syncthreads();

    const int node = blockIdx.x * 4 + (t >> 6);
    if (node >= n) return;
    const int lane = t & 63;
    const int quad = lane >> 4;
    const int c    = lane & 15;

    const int start = row_start[node];
    const int end   = row_start[node + 1];

    float acc = 0.0f;
    for (int j = start + quad; j < end; j += 4) {
        const uint2 ec = sec[j];
        const float4* ap = (const float4*)(edge_attr + (size_t)ec.x * EA_D);
        const float4 a0 = ap[0], a1 = ap[1];
        const float hv = h[(size_t)ec.y * OUT_C + c];

        float d = s_eab[c];
        d = fmaf(a0.x, s_eaw[0 * OUT_C + c], d);
        d = fmaf(a0.y, s_eaw[1 * OUT_C + c], d);
        d = fmaf(a0.z, s_eaw[2 * OUT_C + c], d);
        d = fmaf(a0.w, s_eaw[3 * OUT_C + c], d);
        d = fmaf(a1.x, s_eaw[4 * OUT_C + c], d);
        d = fmaf(a1.y, s_eaw[5 * OUT_C + c], d);
        d = fmaf(a1.z, s_eaw[6 * OUT_C + c], d);
        d = fmaf(a1.w, s_eaw[7 * OUT_C + c], d);
        const float agg = hv * d;

        float s = s_b2;
        #pragma unroll
        for (int jj = 0; jj < OUT_C; ++jj) {
            const float hm = fmaf(agg, s_w1[jj], s_b1[jj]);
            s = fmaf(fmaxf(hm, 0.0f), s_w2[jj], s);
        }

        // softmax over the 16 channels of this quad (shfl stays inside quad)
        float mx = s;
        mx = fmaxf(mx, __shfl_xor(mx, 1));
        mx = fmaxf(mx, __shfl_xor(mx, 2));
        mx = fmaxf(mx, __shfl_xor(mx, 4));
        mx = fmaxf(mx, __shfl_xor(mx, 8));
        const float p = __expf(s - mx);
        float den = p;
        den += __shfl_xor(den, 1);
        den += __shfl_xor(den, 2);
        den += __shfl_xor(den, 4);
        den += __shfl_xor(den, 8);
        acc = fmaf(agg, p / den, acc);
    }

    // combine the 4 quads
    acc += __shfl_xor(acc, 16);
    acc += __shfl_xor(acc, 32);
    if (lane < OUT_C) out[(size_t)node * OUT_C + lane] = acc;
}

extern "C" void kernel_launch(void* const* d_in, const int* in_sizes, int n_in,
                              void* d_out, int out_size, void* d_ws, size_t ws_size,
                              hipStream_t stream)
{
    const float* x          = (const float*)d_in[0];
    const int*   edge_index = (const int*)  d_in[1];
    const float* edge_attr  = (const float*)d_in[2];
    const float* lin_w      = (const float*)d_in[3];
    const float* lin_b      = (const float*)d_in[4];
    const float* ea_w       = (const float*)d_in[5];
    const float* ea_b       = (const float*)d_in[6];
    const float* attn_w1    = (const float*)d_in[7];
    const float* attn_b1    = (const float*)d_in[8];
    const float* attn_w2    = (const float*)d_in[9];
    const float* attn_b2    = (const float*)d_in[10];

    const int n = in_sizes[0] / IN_C;      // 100000
    const int E = in_sizes[1] / 2;         // 400000

    char* ws = (char*)d_ws;
    float* h        = (float*)(ws);                       // N*16*4 = 6.4 MB
    int*   deg      = (int*)  (ws + (size_t) 8 * 1048576);// N ints
    int*   row_start= (int*)  (ws + (size_t) 9 * 1048576);// N+1 ints
    int*   cursor   = (int*)  (ws + (size_t)10 * 1048576);// N ints
    int*   bsum     = (int*)  (ws + (size_t)11 * 1048576);// NB ints
    uint2* sec      = (uint2*)(ws + (size_t)12 * 1048576);// E uint2 = 3.2 MB

    float* out = (float*)d_out;
    const int NB = (n + SCAN_BS - 1) / SCAN_BS;           // 98

    hipMemsetAsync(deg, 0, (size_t)n * sizeof(int), stream);

    h_kernel<<<(n + 15) / 16, 256, 0, stream>>>(x, lin_w, lin_b, h, n);

    hist_kernel<<<(E + 255) / 256, 256, 0, stream>>>(edge_index, deg, E);

    scan_a<<<NB, SCAN_BS, 0, stream>>>(deg, bsum, n);
    scan_b<<<1,  SCAN_BS, 0, stream>>>(bsum, NB, row_start, n);
    scan_c<<<NB, SCAN_BS, 0, stream>>>(deg, bsum, row_start, cursor, n);

    scatter_kernel<<<(E + 255) / 256, 256, 0, stream>>>(edge_index, cursor, sec, E);

    node_kernel<<<(n + 3) / 4, 256, 0, stream>>>(
        sec, row_start, edge_attr, h,
        ea_w, ea_b, attn_w1, attn_b1, attn_w2, attn_b2,
        out, n);
}

// Round 5
// 131.345 us; speedup vs baseline: 1.7279x; 1.7279x over previous
//
#include <hip/hip_runtime.h>

#define IN_C 64
#define OUT_C 16
#define EA_D 8

__device__ __forceinline__ void atomic_add_f32(float* p, float v) {
#if defined(__HIP_PLATFORM_AMD__) || defined(__AMDGCN__)
    unsafeAtomicAdd(p, v);   // global_atomic_add_f32, no CAS loop
#else
    atomicAdd(p, v);
#endif
}

// ---------------- h = x @ lin_w + lin_b ----------------
// block = 256 threads = 16 nodes x 16 channels; all LDS reads are b128.
__global__ __launch_bounds__(256) void h_kernel(
    const float* __restrict__ x,
    const float* __restrict__ lin_w,   // [64,16]
    const float* __restrict__ lin_b,   // [16]
    float* __restrict__ h,             // [N,16]
    int n)
{
    __shared__ float s_x [16][IN_C + 4];   // stride 68 floats: 16B-aligned rows
    __shared__ float s_wt[16][IN_C + 4];   // transposed W: s_wt[c][k]

    const int t = threadIdx.x;

    // stage transposed weights (one-time, conflicts irrelevant)
    for (int i = t; i < IN_C * OUT_C; i += 256)
        s_wt[i & 15][i >> 4] = lin_w[i];

    const int nodeBase = blockIdx.x * 16;
    {
        const int lr = t >> 4;            // row 0..15
        const int k4 = (t & 15) * 4;      // col 0,4,...,60
        const int node = nodeBase + lr;
        float4 v = make_float4(0.f, 0.f, 0.f, 0.f);
        if (node < n) v = *(const float4*)(x + (size_t)node * IN_C + k4);
        *(float4*)(&s_x[lr][k4]) = v;
    }
    __syncthreads();

    const int lr = t >> 4;
    const int c  = t & 15;
    const int node = nodeBase + lr;
    if (node < n) {
        float acc = lin_b[c];
        #pragma unroll
        for (int k4 = 0; k4 < IN_C; k4 += 4) {
            const float4 xv = *(const float4*)(&s_x [lr][k4]);  // broadcast in quad
            const float4 wv = *(const float4*)(&s_wt[c ][k4]);  // <=2-way conflict (free)
            acc = fmaf(xv.x, wv.x, acc);
            acc = fmaf(xv.y, wv.y, acc);
            acc = fmaf(xv.z, wv.z, acc);
            acc = fmaf(xv.w, wv.w, acc);
        }
        h[(size_t)node * OUT_C + c] = acc;
    }
}

// ---------------- per-edge fused kernel: quad-per-edge ----------------
// lane = (edge, channel): 16 consecutive lanes cover one edge's 16 channels.
// w1/b1/w2/b2 read at uniform addresses -> compiler emits scalar loads.
// Softmax via shfl_xor within the 16-lane quad. Scatter naturally grouped:
// 16 lanes hit one 64B out line. No LDS, no barriers.
__global__ __launch_bounds__(256) void edge_kernel(
    const int*   __restrict__ edge_index,  // [2,E]
    const float* __restrict__ edge_attr,   // [E,8]
    const float* __restrict__ ea_w,        // [8,16]
    const float* __restrict__ ea_b,        // [16]
    const float* __restrict__ w1,          // [16]
    const float* __restrict__ b1,          // [16]
    const float* __restrict__ w2,          // [16]
    const float* __restrict__ b2,          // [1]
    const float* __restrict__ h,           // [N,16]
    float*       __restrict__ out,         // [N,16]
    int E)
{
    const int gid = blockIdx.x * 256 + threadIdx.x;
    const int e = gid >> 4;
    const int c = gid & 15;
    if (e >= E) return;

    const int row = edge_index[e] - 1;     // edge_index[0][e] - 1
    const int col = edge_index[E + e];     // edge_index[1][e]

    // 32B broadcast per quad (contiguous across the 4 quads of a wave)
    const float4* ap = (const float4*)(edge_attr + (size_t)e * EA_D);
    const float4 a0 = ap[0], a1 = ap[1];

    // gather: 16 consecutive lanes read one 64B line of h
    const float hv = h[(size_t)col * OUT_C + c];

    // agg = h[col][c] * (edge_attr @ ea_w + ea_b)[c]   (ea_* lane-indexed, L1-hot)
    float d = ea_b[c];
    d = fmaf(a0.x, ea_w[0 * OUT_C + c], d);
    d = fmaf(a0.y, ea_w[1 * OUT_C + c], d);
    d = fmaf(a0.z, ea_w[2 * OUT_C + c], d);
    d = fmaf(a0.w, ea_w[3 * OUT_C + c], d);
    d = fmaf(a1.x, ea_w[4 * OUT_C + c], d);
    d = fmaf(a1.y, ea_w[5 * OUT_C + c], d);
    d = fmaf(a1.z, ea_w[6 * OUT_C + c], d);
    d = fmaf(a1.w, ea_w[7 * OUT_C + c], d);
    const float agg = hv * d;

    // score = b2 + sum_j relu(agg*w1[j]+b1[j])*w2[j]  (weights = scalar loads)
    float s = b2[0];
    #pragma unroll
    for (int j = 0; j < OUT_C; ++j) {
        const float hm = fmaf(agg, w1[j], b1[j]);
        s = fmaf(fmaxf(hm, 0.0f), w2[j], s);
    }

    // softmax over the 16 channels of this quad
    float mx = s;
    mx = fmaxf(mx, __shfl_xor(mx, 1));
    mx = fmaxf(mx, __shfl_xor(mx, 2));
    mx = fmaxf(mx, __shfl_xor(mx, 4));
    mx = fmaxf(mx, __shfl_xor(mx, 8));
    const float p = __expf(s - mx);
    float den = p;
    den += __shfl_xor(den, 1);
    den += __shfl_xor(den, 2);
    den += __shfl_xor(den, 4);
    den += __shfl_xor(den, 8);

    // grouped scatter: one 64B line per quad
    atomic_add_f32(out + (size_t)row * OUT_C + c, agg * (p / den));
}

extern "C" void kernel_launch(void* const* d_in, const int* in_sizes, int n_in,
                              void* d_out, int out_size, void* d_ws, size_t ws_size,
                              hipStream_t stream)
{
    const float* x          = (const float*)d_in[0];
    const int*   edge_index = (const int*)  d_in[1];
    const float* edge_attr  = (const float*)d_in[2];
    const float* lin_w      = (const float*)d_in[3];
    const float* lin_b      = (const float*)d_in[4];
    const float* ea_w       = (const float*)d_in[5];
    const float* ea_b       = (const float*)d_in[6];
    const float* attn_w1    = (const float*)d_in[7];
    const float* attn_b1    = (const float*)d_in[8];
    const float* attn_w2    = (const float*)d_in[9];
    const float* attn_b2    = (const float*)d_in[10];

    const int n = in_sizes[0] / IN_C;      // 100000
    const int E = in_sizes[1] / 2;         // 400000

    float* h   = (float*)d_ws;             // [N,16] = 6.4 MB
    float* out = (float*)d_out;

    hipMemsetAsync(out, 0, (size_t)out_size * sizeof(float), stream);

    h_kernel<<<(n + 15) / 16, 256, 0, stream>>>(x, lin_w, lin_b, h, n);

    // 16 lanes per edge
    const long long threads = (long long)E * OUT_C;
    edge_kernel<<<(int)((threads + 255) / 256), 256, 0, stream>>>(
        edge_index, edge_attr, ea_w, ea_b,
        attn_w1, attn_b1, attn_w2, attn_b2,
        h, out, E);
}

// Round 6
// 129.672 us; speedup vs baseline: 1.7502x; 1.0129x over previous
//
#include <hip/hip_runtime.h>

#define IN_C 64
#define OUT_C 16
#define EA_D 8

__device__ __forceinline__ void atomic_add_f32(float* p, float v) {
#if defined(__HIP_PLATFORM_AMD__) || defined(__AMDGCN__)
    unsafeAtomicAdd(p, v);   // global_atomic_add_f32, no CAS loop
#else
    atomicAdd(p, v);
#endif
}

// ---------------- h = x @ lin_w + lin_b  (also zeroes out[]) ----------------
// block = 256 threads = 16 nodes x 16 channels; all LDS reads are b128.
// Grid covers every (node, channel) exactly once -> fuse out[]=0 here and
// drop the separate memset dispatch (edge_kernel runs after us in-stream).
__global__ __launch_bounds__(256) void h_kernel(
    const float* __restrict__ x,
    const float* __restrict__ lin_w,   // [64,16]
    const float* __restrict__ lin_b,   // [16]
    float* __restrict__ h,             // [N,16]
    float* __restrict__ out,           // [N,16] zero-init
    int n)
{
    __shared__ float s_x [16][IN_C + 4];   // stride 68 floats: 16B-aligned rows
    __shared__ float s_wt[16][IN_C + 4];   // transposed W: s_wt[c][k]

    const int t = threadIdx.x;
    const int nodeBase = blockIdx.x * 16;

    // zero out[] early: store latency hides under the FMA loop below
    {
        const int idx = nodeBase * OUT_C + t;      // 256 consecutive elements
        if (idx < n * OUT_C) out[idx] = 0.0f;
    }

    // stage transposed weights (one-time, conflicts irrelevant)
    for (int i = t; i < IN_C * OUT_C; i += 256)
        s_wt[i & 15][i >> 4] = lin_w[i];

    {
        const int lr = t >> 4;            // row 0..15
        const int k4 = (t & 15) * 4;      // col 0,4,...,60
        const int node = nodeBase + lr;
        float4 v = make_float4(0.f, 0.f, 0.f, 0.f);
        if (node < n) v = *(const float4*)(x + (size_t)node * IN_C + k4);
        *(float4*)(&s_x[lr][k4]) = v;
    }
    __syncthreads();

    const int lr = t >> 4;
    const int c  = t & 15;
    const int node = nodeBase + lr;
    if (node < n) {
        float acc = lin_b[c];
        #pragma unroll
        for (int k4 = 0; k4 < IN_C; k4 += 4) {
            const float4 xv = *(const float4*)(&s_x [lr][k4]);  // broadcast in quad
            const float4 wv = *(const float4*)(&s_wt[c ][k4]);  // <=2-way conflict (free)
            acc = fmaf(xv.x, wv.x, acc);
            acc = fmaf(xv.y, wv.y, acc);
            acc = fmaf(xv.z, wv.z, acc);
            acc = fmaf(xv.w, wv.w, acc);
        }
        h[(size_t)node * OUT_C + c] = acc;
    }
}

// ---------------- per-edge fused kernel: quad-per-edge ----------------
// lane = (edge, channel): 16 consecutive lanes cover one edge's 16 channels.
// ea_w/ea_b staged in LDS (uniform-per-quad reads = broadcast, conflict-free),
// w1/b1/w2/b2 at uniform addresses -> scalar loads. Softmax via shfl_xor
// within the 16-lane quad. Scatter naturally grouped: 16 lanes = one 64B line.
__global__ __launch_bounds__(256) void edge_kernel(
    const int*   __restrict__ edge_index,  // [2,E]
    const float* __restrict__ edge_attr,   // [E,8]
    const float* __restrict__ ea_w,        // [8,16]
    const float* __restrict__ ea_b,        // [16]
    const float* __restrict__ w1,          // [16]
    const float* __restrict__ b1,          // [16]
    const float* __restrict__ w2,          // [16]
    const float* __restrict__ b2,          // [1]
    const float* __restrict__ h,           // [N,16]
    float*       __restrict__ out,         // [N,16]
    int E)
{
    __shared__ float s_eaw[EA_D * OUT_C];  // 128
    __shared__ float s_eab[OUT_C];

    const int t = threadIdx.x;
    if (t < EA_D * OUT_C)     s_eaw[t]       = ea_w[t];
    else if (t < 128 + OUT_C) s_eab[t - 128] = ea_b[t - 128];
    __syncthreads();

    const int gid = blockIdx.x * 256 + t;
    const int e = gid >> 4;
    const int c = gid & 15;
    if (e >= E) return;

    const int row = edge_index[e] - 1;     // edge_index[0][e] - 1
    const int col = edge_index[E + e];     // edge_index[1][e]

    // 32B broadcast per quad (contiguous across the 4 quads of a wave)
    const float4* ap = (const float4*)(edge_attr + (size_t)e * EA_D);
    const float4 a0 = ap[0], a1 = ap[1];

    // gather: 16 consecutive lanes read one 64B line of h
    const float hv = h[(size_t)col * OUT_C + c];

    // agg = h[col][c] * (edge_attr @ ea_w + ea_b)[c]
    float d = s_eab[c];
    d = fmaf(a0.x, s_eaw[0 * OUT_C + c], d);
    d = fmaf(a0.y, s_eaw[1 * OUT_C + c], d);
    d = fmaf(a0.z, s_eaw[2 * OUT_C + c], d);
    d = fmaf(a0.w, s_eaw[3 * OUT_C + c], d);
    d = fmaf(a1.x, s_eaw[4 * OUT_C + c], d);
    d = fmaf(a1.y, s_eaw[5 * OUT_C + c], d);
    d = fmaf(a1.z, s_eaw[6 * OUT_C + c], d);
    d = fmaf(a1.w, s_eaw[7 * OUT_C + c], d);
    const float agg = hv * d;

    // score = b2 + sum_j relu(agg*w1[j]+b1[j])*w2[j]  (weights = scalar loads)
    float s = b2[0];
    #pragma unroll
    for (int j = 0; j < OUT_C; ++j) {
        const float hm = fmaf(agg, w1[j], b1[j]);
        s = fmaf(fmaxf(hm, 0.0f), w2[j], s);
    }

    // softmax over the 16 channels of this quad
    float mx = s;
    mx = fmaxf(mx, __shfl_xor(mx, 1));
    mx = fmaxf(mx, __shfl_xor(mx, 2));
    mx = fmaxf(mx, __shfl_xor(mx, 4));
    mx = fmaxf(mx, __shfl_xor(mx, 8));
    const float p = __expf(s - mx);
    float den = p;
    den += __shfl_xor(den, 1);
    den += __shfl_xor(den, 2);
    den += __shfl_xor(den, 4);
    den += __shfl_xor(den, 8);

    // grouped scatter: one 64B line per quad
    atomic_add_f32(out + (size_t)row * OUT_C + c, agg * (p / den));
}

extern "C" void kernel_launch(void* const* d_in, const int* in_sizes, int n_in,
                              void* d_out, int out_size, void* d_ws, size_t ws_size,
                              hipStream_t stream)
{
    const float* x          = (const float*)d_in[0];
    const int*   edge_index = (const int*)  d_in[1];
    const float* edge_attr  = (const float*)d_in[2];
    const float* lin_w      = (const float*)d_in[3];
    const float* lin_b      = (const float*)d_in[4];
    const float* ea_w       = (const float*)d_in[5];
    const float* ea_b       = (const float*)d_in[6];
    const float* attn_w1    = (const float*)d_in[7];
    const float* attn_b1    = (const float*)d_in[8];
    const float* attn_w2    = (const float*)d_in[9];
    const float* attn_b2    = (const float*)d_in[10];

    const int n = in_sizes[0] / IN_C;      // 100000
    const int E = in_sizes[1] / 2;         // 400000

    float* h   = (float*)d_ws;             // [N,16] = 6.4 MB
    float* out = (float*)d_out;

    // h_kernel zeroes out[] (grid covers every out element exactly once)
    h_kernel<<<(n + 15) / 16, 256, 0, stream>>>(x, lin_w, lin_b, h, out, n);

    // 16 lanes per edge
    const long long threads = (long long)E * OUT_C;
    edge_kernel<<<(int)((threads + 255) / 256), 256, 0, stream>>>(
        edge_index, edge_attr, ea_w, ea_b,
        attn_w1, attn_b1, attn_w2, attn_b2,
        h, out, E);
}